// Round 1
// baseline (2265.581 us; speedup 1.0000x reference)
//
#include <hip/hip_runtime.h>

// Problem constants (fixed by the reference's setup_inputs)
#define NB 2          // batch
#define NN 262144     // events per batch
#define ND 10         // temporal bins (base)
#define NR 11         // warp references (base + 1)
#define HH 256
#define WW 256
#define HWSZ 65536    // HH*WW
#define EPSF 1e-9f

// ws layout:
//   float2 cells[NB*2*NR*HWSZ]   -- (iwe, iwt) interleaved, 23,068,672 bytes
//   float  accum[NB*NR*2]        -- (sumsq, inside_count) per (b,r)

__global__ __launch_bounds__(256) void cm_scatter(
    const float* __restrict__ events,
    const float* __restrict__ flow,
    float2* __restrict__ cells)
{
    int gid = blockIdx.x * blockDim.x + threadIdx.x;
    if (gid >= NB * NN) return;
    int b = gid >> 18;  // NN = 2^18

    const float* e = events + (size_t)gid * 5;
    float x  = e[0];
    float y  = e[1];
    float t  = e[2];
    float ts = e[3];
    float p  = e[4];

    // event's temporal bin
    int zi = (int)floorf(t);
    zi = zi < 0 ? 0 : (zi > ND - 1 ? ND - 1 : zi);

    // border-clamped bilinear sample of flow at (x, y)
    int x0 = (int)floorf(x);
    x0 = x0 < 0 ? 0 : (x0 > WW - 2 ? WW - 2 : x0);
    int y0 = (int)floorf(y);
    y0 = y0 < 0 ? 0 : (y0 > HH - 2 ? HH - 2 : y0);
    float fx = fminf(fmaxf(x - (float)x0, 0.0f), 1.0f);
    float fy = fminf(fmaxf(y - (float)y0, 0.0f), 1.0f);

    const float2* f2 = (const float2*)flow + ((size_t)b * ND + zi) * HWSZ;
    float2 f00 = f2[y0 * WW + x0];
    float2 f01 = f2[y0 * WW + x0 + 1];
    float2 f10 = f2[(y0 + 1) * WW + x0];
    float2 f11 = f2[(y0 + 1) * WW + x0 + 1];
    float w00 = (1.0f - fx) * (1.0f - fy);
    float w01 = fx * (1.0f - fy);
    float w10 = (1.0f - fx) * fy;
    float w11 = fx * fy;
    float flx = w00 * f00.x + w01 * f01.x + w10 * f10.x + w11 * f11.x;
    float fly = w00 * f00.y + w01 * f01.y + w10 * f10.y + w11 * f11.y;

    int pi = (int)p;
    pi = pi < 0 ? 0 : (pi > 1 ? 1 : pi);
    float* chan = (float*)(cells + (size_t)(b * 2 + pi) * NR * HWSZ);

    #pragma unroll
    for (int r = 0; r < NR; ++r) {
        float dt = (float)r - t;
        float wx = x + dt * flx;
        float wy = y + dt * fly;
        float fwx = floorf(wx);
        float fwy = floorf(wy);
        int xi = (int)fwx;
        int yi = (int)fwy;
        float ax = wx - fwx;
        float ay = wy - fwy;
        float c00 = (1.0f - ax) * (1.0f - ay);
        float c01 = ax * (1.0f - ay);
        float c10 = (1.0f - ax) * ay;
        float c11 = ax * ay;
        bool vx0 = (xi >= 0) && (xi < WW);
        bool vx1 = (xi + 1 >= 0) && (xi + 1 < WW);
        bool vy0 = (yi >= 0) && (yi < HH);
        bool vy1 = (yi + 1 >= 0) && (yi + 1 < HH);
        float* cb = chan + (size_t)r * (HWSZ * 2);
        if (vy0) {
            float* row = cb + (size_t)yi * (WW * 2);
            if (vx0) { atomicAdd(row + xi * 2,       c00); atomicAdd(row + xi * 2 + 1,       c00 * ts); }
            if (vx1) { atomicAdd(row + (xi + 1) * 2, c01); atomicAdd(row + (xi + 1) * 2 + 1, c01 * ts); }
        }
        if (vy1) {
            float* row = cb + (size_t)(yi + 1) * (WW * 2);
            if (vx0) { atomicAdd(row + xi * 2,       c10); atomicAdd(row + xi * 2 + 1,       c10 * ts); }
            if (vx1) { atomicAdd(row + (xi + 1) * 2, c11); atomicAdd(row + (xi + 1) * 2 + 1, c11 * ts); }
        }
    }
}

__global__ __launch_bounds__(256) void cm_reduce(
    const float2* __restrict__ cells,
    float* __restrict__ accum)
{
    int px = blockIdx.x * 256 + threadIdx.x;  // pixel in [0, HWSZ)
    int br = blockIdx.y;                      // (b*NR + r)
    int b = br / NR;
    int r = br - b * NR;
    size_t i0 = ((size_t)(b * 2 + 0) * NR + r) * HWSZ + px;
    size_t i1 = ((size_t)(b * 2 + 1) * NR + r) * HWSZ + px;
    float2 c0 = cells[i0];
    float2 c1 = cells[i1];
    float a0 = c0.y / (c0.x + EPSF);
    float a1 = c1.y / (c1.x + EPSF);
    float ss = a0 * a0 + a1 * a1;
    float ins = ((c0.x + c1.x) > 0.0f) ? 1.0f : 0.0f;

    // wave (64-lane) reduction
    #pragma unroll
    for (int off = 32; off > 0; off >>= 1) {
        ss  += __shfl_down(ss, off, 64);
        ins += __shfl_down(ins, off, 64);
    }
    __shared__ float s_ss[4];
    __shared__ float s_in[4];
    int lane = threadIdx.x & 63;
    int wv = threadIdx.x >> 6;
    if (lane == 0) { s_ss[wv] = ss; s_in[wv] = ins; }
    __syncthreads();
    if (threadIdx.x == 0) {
        float tss = s_ss[0] + s_ss[1] + s_ss[2] + s_ss[3];
        float tin = s_in[0] + s_in[1] + s_in[2] + s_in[3];
        atomicAdd(&accum[br * 2],     tss);
        atomicAdd(&accum[br * 2 + 1], tin);
    }
}

__global__ void cm_final(const float* __restrict__ accum, float* __restrict__ out)
{
    int i = threadIdx.x;
    if (i < NB * NR) {
        out[i] = accum[i * 2] / (accum[i * 2 + 1] + EPSF);
    }
}

extern "C" void kernel_launch(void* const* d_in, const int* in_sizes, int n_in,
                              void* d_out, int out_size, void* d_ws, size_t ws_size,
                              hipStream_t stream) {
    const float* events = (const float*)d_in[0];
    const float* flow   = (const float*)d_in[1];

    float2* cells = (float2*)d_ws;
    size_t cells_bytes = (size_t)NB * 2 * NR * HWSZ * sizeof(float2);  // 23,068,672
    float* accum = (float*)((char*)d_ws + cells_bytes);
    size_t accum_bytes = (size_t)NB * NR * 2 * sizeof(float);

    hipMemsetAsync(d_ws, 0, cells_bytes + accum_bytes, stream);

    int nev = NB * NN;
    cm_scatter<<<(nev + 255) / 256, 256, 0, stream>>>(events, flow, cells);

    dim3 rgrid(HWSZ / 256, NB * NR);
    cm_reduce<<<rgrid, 256, 0, stream>>>(cells, accum);

    cm_final<<<1, 64, 0, stream>>>(accum, (float*)d_out);
}

// Round 2
// 2259.258 us; speedup vs baseline: 1.0028x; 1.0028x over previous
//
#include <hip/hip_runtime.h>

// Problem constants (fixed by the reference's setup_inputs)
#define NB 2          // batch
#define NN 262144     // events per batch
#define ND 10         // temporal bins (base)
#define NR 11         // warp references (base + 1)
#define HH 256
#define WW 256
#define HWSZ 65536    // HH*WW
#define EPSF 1e-9f

// ws layout:
//   float2 cells[NB*2*NR*HWSZ]   -- (iwe, iwt) interleaved, 23,068,672 bytes
//   float  accum[NB*NR*2]        -- (sumsq, inside_count) per (b,r)

// Hardware fp32 atomic add (global_atomic_add_f32, no return, fire-and-forget).
// Plain atomicAdd(float*) compiles to a CAS retry loop without
// -munsafe-fp-atomics -- that was the 2.1 ms bottleneck in R1.
__device__ __forceinline__ void hw_fadd(float* p, float v) {
    unsafeAtomicAdd(p, v);
}

__global__ __launch_bounds__(256) void cm_scatter(
    const float* __restrict__ events,
    const float* __restrict__ flow,
    float2* __restrict__ cells)
{
    int gid = blockIdx.x * blockDim.x + threadIdx.x;
    if (gid >= NB * NN) return;
    int b = gid >> 18;  // NN = 2^18

    const float* e = events + (size_t)gid * 5;
    float x  = e[0];
    float y  = e[1];
    float t  = e[2];
    float ts = e[3];
    float p  = e[4];

    // event's temporal bin
    int zi = (int)floorf(t);
    zi = zi < 0 ? 0 : (zi > ND - 1 ? ND - 1 : zi);

    // border-clamped bilinear sample of flow at (x, y)
    int x0 = (int)floorf(x);
    x0 = x0 < 0 ? 0 : (x0 > WW - 2 ? WW - 2 : x0);
    int y0 = (int)floorf(y);
    y0 = y0 < 0 ? 0 : (y0 > HH - 2 ? HH - 2 : y0);
    float fx = fminf(fmaxf(x - (float)x0, 0.0f), 1.0f);
    float fy = fminf(fmaxf(y - (float)y0, 0.0f), 1.0f);

    const float2* f2 = (const float2*)flow + ((size_t)b * ND + zi) * HWSZ;
    float2 f00 = f2[y0 * WW + x0];
    float2 f01 = f2[y0 * WW + x0 + 1];
    float2 f10 = f2[(y0 + 1) * WW + x0];
    float2 f11 = f2[(y0 + 1) * WW + x0 + 1];
    float w00 = (1.0f - fx) * (1.0f - fy);
    float w01 = fx * (1.0f - fy);
    float w10 = (1.0f - fx) * fy;
    float w11 = fx * fy;
    float flx = w00 * f00.x + w01 * f01.x + w10 * f10.x + w11 * f11.x;
    float fly = w00 * f00.y + w01 * f01.y + w10 * f10.y + w11 * f11.y;

    int pi = (int)p;
    pi = pi < 0 ? 0 : (pi > 1 ? 1 : pi);
    float* chan = (float*)(cells + (size_t)(b * 2 + pi) * NR * HWSZ);

    #pragma unroll
    for (int r = 0; r < NR; ++r) {
        float dt = (float)r - t;
        float wx = x + dt * flx;
        float wy = y + dt * fly;
        float fwx = floorf(wx);
        float fwy = floorf(wy);
        int xi = (int)fwx;
        int yi = (int)fwy;
        float ax = wx - fwx;
        float ay = wy - fwy;
        float c00 = (1.0f - ax) * (1.0f - ay);
        float c01 = ax * (1.0f - ay);
        float c10 = (1.0f - ax) * ay;
        float c11 = ax * ay;
        bool vx0 = (xi >= 0) && (xi < WW);
        bool vx1 = (xi + 1 >= 0) && (xi + 1 < WW);
        bool vy0 = (yi >= 0) && (yi < HH);
        bool vy1 = (yi + 1 >= 0) && (yi + 1 < HH);
        float* cb = chan + (size_t)r * (HWSZ * 2);
        if (vy0) {
            float* row = cb + (size_t)yi * (WW * 2);
            if (vx0) { hw_fadd(row + xi * 2,       c00); hw_fadd(row + xi * 2 + 1,       c00 * ts); }
            if (vx1) { hw_fadd(row + (xi + 1) * 2, c01); hw_fadd(row + (xi + 1) * 2 + 1, c01 * ts); }
        }
        if (vy1) {
            float* row = cb + (size_t)(yi + 1) * (WW * 2);
            if (vx0) { hw_fadd(row + xi * 2,       c10); hw_fadd(row + xi * 2 + 1,       c10 * ts); }
            if (vx1) { hw_fadd(row + (xi + 1) * 2, c11); hw_fadd(row + (xi + 1) * 2 + 1, c11 * ts); }
        }
    }
}

__global__ __launch_bounds__(256) void cm_reduce(
    const float2* __restrict__ cells,
    float* __restrict__ accum)
{
    int px = blockIdx.x * 256 + threadIdx.x;  // pixel in [0, HWSZ)
    int br = blockIdx.y;                      // (b*NR + r)
    int b = br / NR;
    int r = br - b * NR;
    size_t i0 = ((size_t)(b * 2 + 0) * NR + r) * HWSZ + px;
    size_t i1 = ((size_t)(b * 2 + 1) * NR + r) * HWSZ + px;
    float2 c0 = cells[i0];
    float2 c1 = cells[i1];
    float a0 = c0.y / (c0.x + EPSF);
    float a1 = c1.y / (c1.x + EPSF);
    float ss = a0 * a0 + a1 * a1;
    float ins = ((c0.x + c1.x) > 0.0f) ? 1.0f : 0.0f;

    // wave (64-lane) reduction
    #pragma unroll
    for (int off = 32; off > 0; off >>= 1) {
        ss  += __shfl_down(ss, off, 64);
        ins += __shfl_down(ins, off, 64);
    }
    __shared__ float s_ss[4];
    __shared__ float s_in[4];
    int lane = threadIdx.x & 63;
    int wv = threadIdx.x >> 6;
    if (lane == 0) { s_ss[wv] = ss; s_in[wv] = ins; }
    __syncthreads();
    if (threadIdx.x == 0) {
        float tss = s_ss[0] + s_ss[1] + s_ss[2] + s_ss[3];
        float tin = s_in[0] + s_in[1] + s_in[2] + s_in[3];
        atomicAdd(&accum[br * 2],     tss);
        atomicAdd(&accum[br * 2 + 1], tin);
    }
}

__global__ void cm_final(const float* __restrict__ accum, float* __restrict__ out)
{
    int i = threadIdx.x;
    if (i < NB * NR) {
        out[i] = accum[i * 2] / (accum[i * 2 + 1] + EPSF);
    }
}

extern "C" void kernel_launch(void* const* d_in, const int* in_sizes, int n_in,
                              void* d_out, int out_size, void* d_ws, size_t ws_size,
                              hipStream_t stream) {
    const float* events = (const float*)d_in[0];
    const float* flow   = (const float*)d_in[1];

    float2* cells = (float2*)d_ws;
    size_t cells_bytes = (size_t)NB * 2 * NR * HWSZ * sizeof(float2);  // 23,068,672
    float* accum = (float*)((char*)d_ws + cells_bytes);
    size_t accum_bytes = (size_t)NB * NR * 2 * sizeof(float);

    hipMemsetAsync(d_ws, 0, cells_bytes + accum_bytes, stream);

    int nev = NB * NN;
    cm_scatter<<<(nev + 255) / 256, 256, 0, stream>>>(events, flow, cells);

    dim3 rgrid(HWSZ / 256, NB * NR);
    cm_reduce<<<rgrid, 256, 0, stream>>>(cells, accum);

    cm_final<<<1, 64, 0, stream>>>(accum, (float*)d_out);
}

// Round 4
// 466.507 us; speedup vs baseline: 4.8565x; 4.8429x over previous
//
#include <hip/hip_runtime.h>

// Problem constants (fixed by the reference's setup_inputs)
#define NB 2          // batch
#define NN 262144     // events per batch (2^18)
#define ND 10         // temporal bins (base)
#define NR 11         // warp references (base + 1)
#define HH 256
#define WW 256
#define HWSZ 65536
#define SROWS 16      // rows per y-strip
#define NSTRIP 16     // 256 / SROWS
#define EPSF 1e-9f

// ws layout (12.6 MB total -- deliberately under the 23.07 MB proven good in
// R1/R2; R3's 35.7 MB layout is the suspected container-killer):
//   float4 rec[NB*NN]   -- (ax, ay, dx, dy): warped pos at ref r = (ax+r*dx, ay+r*dy)
//   float2 tsp[NB*NN]   -- (t_stamp, polarity)
//   float  accum[64]    -- (sumsq, inside) per (b,r)
//
// R1/R2 lesson: 46M scattered device-scope fp32 atomics run at ~22 G/s no
// matter how emitted (memory-side execution) -> 2.1 ms. This version has ZERO
// per-event global atomics: each (b, r, 16x256 strip) is owned by one block,
// accumulated in 64 KB LDS, and reduced to 2 scalars in-block. The IWE/IWT
// images never touch global memory at all.

__global__ __launch_bounds__(256) void cm_prep(
    const float* __restrict__ events,
    const float* __restrict__ flow,
    float4* __restrict__ rec,
    float2* __restrict__ tsp)
{
    int gid = blockIdx.x * 256 + threadIdx.x;
    if (gid >= NB * NN) return;
    int b = gid >> 18;

    const float* e = events + (size_t)gid * 5;
    float x  = e[0];
    float y  = e[1];
    float t  = e[2];
    float ts = e[3];
    float p  = e[4];

    int zi = (int)floorf(t);
    zi = zi < 0 ? 0 : (zi > ND - 1 ? ND - 1 : zi);

    int x0 = (int)floorf(x);
    x0 = x0 < 0 ? 0 : (x0 > WW - 2 ? WW - 2 : x0);
    int y0 = (int)floorf(y);
    y0 = y0 < 0 ? 0 : (y0 > HH - 2 ? HH - 2 : y0);
    float fx = fminf(fmaxf(x - (float)x0, 0.0f), 1.0f);
    float fy = fminf(fmaxf(y - (float)y0, 0.0f), 1.0f);

    const float2* f2 = (const float2*)flow + ((size_t)b * ND + zi) * HWSZ;
    float2 f00 = f2[y0 * WW + x0];
    float2 f01 = f2[y0 * WW + x0 + 1];
    float2 f10 = f2[(y0 + 1) * WW + x0];
    float2 f11 = f2[(y0 + 1) * WW + x0 + 1];
    float w00 = (1.0f - fx) * (1.0f - fy);
    float w01 = fx * (1.0f - fy);
    float w10 = (1.0f - fx) * fy;
    float w11 = fx * fy;
    float flx = w00 * f00.x + w01 * f01.x + w10 * f10.x + w11 * f11.x;
    float fly = w00 * f00.y + w01 * f01.y + w10 * f10.y + w11 * f11.y;

    rec[gid] = make_float4(fmaf(-t, flx, x), fmaf(-t, fly, y), flx, fly);
    tsp[gid] = make_float2(ts, p);
}

__global__ __launch_bounds__(512) void cm_scan(
    const float4* __restrict__ rec,
    const float2* __restrict__ tsp,
    float* __restrict__ accum)
{
    __shared__ float2 acc[2 * SROWS * WW];  // 64 KB: pol x 16 x 256 (iwe, iwt)

    int bi  = blockIdx.x;                  // 0 .. NB*NR*NSTRIP-1
    int b   = bi / (NR * NSTRIP);
    int rem = bi - b * (NR * NSTRIP);
    int r   = rem >> 4;
    int st  = rem & 15;
    int ty0  = st * SROWS;
    int tyhi = ty0 + SROWS;                // exclusive

    for (int i = threadIdx.x; i < 2 * SROWS * WW; i += 512)
        acc[i] = make_float2(0.0f, 0.0f);
    __syncthreads();

    const float rf = (float)r;
    const int base = b * NN;

    for (int i = threadIdx.x; i < NN; i += 512) {
        float4 e = rec[base + i];
        float wx = fmaf(rf, e.z, e.x);
        float wy = fmaf(rf, e.w, e.y);
        float fwx = floorf(wx);
        float fwy = floorf(wy);
        int xi = (int)fwx;
        int yi = (int)fwy;
        // patch misses this strip (or is fully x-out-of-range) -> reject
        if (yi + 1 < ty0 || yi >= tyhi || xi + 1 < 0 || xi >= WW) continue;

        float ax = wx - fwx;
        float ay = wy - fwy;
        float2 tp = tsp[base + i];
        float ts = tp.x;
        int pi = (int)tp.y;
        pi = pi < 0 ? 0 : (pi > 1 ? 1 : pi);
        float* ap = (float*)acc + pi * (SROWS * WW * 2);

        float c00 = (1.0f - ax) * (1.0f - ay);
        float c01 = ax * (1.0f - ay);
        float c10 = (1.0f - ax) * ay;
        float c11 = ax * ay;

        #define CM_CORNER(XI, YI, WV)                                        \
            if ((XI) >= 0 && (XI) < WW && (YI) >= ty0 && (YI) < tyhi) {      \
                int li = ((YI) - ty0) * WW + (XI);                           \
                atomicAdd(ap + 2 * li,     (WV));                            \
                atomicAdd(ap + 2 * li + 1, (WV) * ts);                       \
            }
        CM_CORNER(xi,     yi,     c00)
        CM_CORNER(xi + 1, yi,     c01)
        CM_CORNER(xi,     yi + 1, c10)
        CM_CORNER(xi + 1, yi + 1, c11)
        #undef CM_CORNER
    }
    __syncthreads();

    // fused reduction: this block exclusively owns its strip for both
    // polarities -> compute sum((iwt/(iwe+eps))^2) and count(iwe0+iwe1 > 0)
    float ss = 0.0f, ins = 0.0f;
    for (int i = threadIdx.x; i < SROWS * WW; i += 512) {
        float2 c0 = acc[i];
        float2 c1 = acc[SROWS * WW + i];
        float a0 = c0.y / (c0.x + EPSF);
        float a1 = c1.y / (c1.x + EPSF);
        ss += a0 * a0 + a1 * a1;
        ins += ((c0.x + c1.x) > 0.0f) ? 1.0f : 0.0f;
    }
    #pragma unroll
    for (int off = 32; off > 0; off >>= 1) {
        ss  += __shfl_down(ss, off, 64);
        ins += __shfl_down(ins, off, 64);
    }
    __syncthreads();  // all LDS reads done before reusing acc[] for partials
    int lane = threadIdx.x & 63;
    int wv = threadIdx.x >> 6;
    if (lane == 0) acc[wv] = make_float2(ss, ins);
    __syncthreads();
    if (threadIdx.x == 0) {
        float tss = 0.0f, tin = 0.0f;
        #pragma unroll
        for (int w = 0; w < 8; ++w) { tss += acc[w].x; tin += acc[w].y; }
        int br = b * NR + r;
        atomicAdd(&accum[br * 2],     tss);  // 704 total atomics -- negligible
        atomicAdd(&accum[br * 2 + 1], tin);
    }
}

__global__ void cm_final(const float* __restrict__ accum, float* __restrict__ out)
{
    int i = threadIdx.x;
    if (i < NB * NR) {
        out[i] = accum[i * 2] / (accum[i * 2 + 1] + EPSF);
    }
}

extern "C" void kernel_launch(void* const* d_in, const int* in_sizes, int n_in,
                              void* d_out, int out_size, void* d_ws, size_t ws_size,
                              hipStream_t stream) {
    const float* events = (const float*)d_in[0];
    const float* flow   = (const float*)d_in[1];

    char* ws = (char*)d_ws;
    float4* rec = (float4*)ws;
    size_t rec_bytes = (size_t)NB * NN * sizeof(float4);   // 8,388,608
    float2* tsp = (float2*)(ws + rec_bytes);
    size_t tsp_bytes = (size_t)NB * NN * sizeof(float2);   // 4,194,304
    float* accum = (float*)(ws + rec_bytes + tsp_bytes);
    size_t accum_bytes = 256;                              // 44 floats, padded

    hipMemsetAsync(accum, 0, accum_bytes, stream);

    cm_prep<<<(NB * NN + 255) / 256, 256, 0, stream>>>(events, flow, rec, tsp);

    cm_scan<<<NB * NR * NSTRIP, 512, 0, stream>>>(rec, tsp, accum);

    cm_final<<<1, 64, 0, stream>>>(accum, (float*)d_out);
}